// Round 1
// baseline (302.717 us; speedup 1.0000x reference)
//
#include <hip/hip_runtime.h>
#include <hip/hip_bf16.h>

#define BATCH 8
#define CCH 1024
#define NHW 4096
#define SCALE 5.0f   // 1/TEMPERATURE
#define ROWS (BATCH * CCH)

typedef unsigned char u8;
typedef unsigned int u32;
typedef __attribute__((ext_vector_type(4))) float float4v;
typedef __attribute__((ext_vector_type(4))) u32 uint4v;
typedef __attribute__((ext_vector_type(4))) int i32x4;
typedef __attribute__((ext_vector_type(8))) int i32x8;

__device__ __forceinline__ void async_load16(const void* gsrc, void* ldst) {
    __builtin_amdgcn_global_load_lds(
        (__attribute__((address_space(1))) void*)gsrc,
        (__attribute__((address_space(3))) void*)ldst,
        16, 0, 0);
}

// pack 4 floats -> 4 OCP e4m3 bytes
__device__ __forceinline__ u32 pk4_fp8(float a, float b, float c, float d) {
    u32 v = __builtin_amdgcn_cvt_pk_fp8_f32(a, b, 0, false);
    v = __builtin_amdgcn_cvt_pk_fp8_f32(c, d, v, true);
    return v;
}

__device__ __forceinline__ float ssq4_fp8(u32 q) {
    float d0 = __builtin_amdgcn_cvt_f32_fp8(q, 0);
    float d1 = __builtin_amdgcn_cvt_f32_fp8(q, 1);
    float d2 = __builtin_amdgcn_cvt_f32_fp8(q, 2);
    float d3 = __builtin_amdgcn_cvt_f32_fp8(q, 3);
    return d0 * d0 + d1 * d1 + d2 * d2 + d3 * d3;
}

// One block per row: quantize x -> fp8, diag = 5*sum(q(x)^2) from QUANTIZED
// values (so the MFMA diagonal dot cancels), zero l_acc (+ completion counter).
template <bool CONVERT>
__global__ __launch_bounds__(256) void prep_kernel(const float* __restrict__ x,
                                                   u8* __restrict__ xq,
                                                   float* __restrict__ diag,
                                                   float* __restrict__ l_acc,
                                                   u32* __restrict__ counter) {
    const int row = blockIdx.x;          // 0..8191
    const int tid = threadIdx.x;
    const float* src = x + (size_t)row * NHW;
    float ssum = 0.f;
#pragma unroll
    for (int p = 0; p < 4; ++p) {
        const int idx = p * 1024 + tid * 4;
        float4 v = *(const float4*)(src + idx);
        const u32 q = pk4_fp8(v.x, v.y, v.z, v.w);
        ssum += ssq4_fp8(q);
        if (CONVERT) *(u32*)(xq + (size_t)row * NHW + idx) = q;
    }
#pragma unroll
    for (int m = 1; m < 64; m <<= 1) ssum += __shfl_xor(ssum, m);
    __shared__ float red[4];
    if ((tid & 63) == 0) red[tid >> 6] = ssum;
    __syncthreads();
    if (tid == 0) {
        diag[row] = (red[0] + red[1] + red[2] + red[3]) * SCALE;
        l_acc[row] = 0.f;
        if (row == 0) *counter = 0;
    }
}

// Symmetric Gram, fp8 e4m3, 128x64 tiles over upper triangle (bj2 >= 2*bi),
// BK=128, double-buffered, prefetch-before-compute. Inner loop now uses the
// MX-scaled mfma_scale_f32_16x16x128_f8f6f4 with unit scales (e8m0=127),
// which runs at ~2.28x the non-scaled fp8 MFMA rate: one K=128 step of
// 8 MFMAs + 12 ds_read_b128 replaces 4 K=32 steps of 32 MFMAs + 24 b64.
// A/B fragment: lane holds row (lane&15), k-bytes (lane>>4)*32..+32 =
// swizzled 16B chunks {2q, 2q+1}. C/D layout unchanged (shape-determined).
// LDS: row = 128 B = 8 chunks of 16 B; chunk (r, kc) at slot kc ^ (r&7).
// Tiles with bj2 in {2bi, 2bi+1}: B rows subset of A rows -> alias As.
// Last block to finish (device counter) performs the scalar finalize.
template <bool QSRC>
__global__ __launch_bounds__(256) void gram_kernel(const u8* __restrict__ Xq,
                                                   const float* __restrict__ Xf,
                                                   const float* __restrict__ diag,
                                                   float* __restrict__ l_acc,
                                                   float* __restrict__ num,
                                                   u32* __restrict__ counter,
                                                   float* __restrict__ out) {
    __shared__ __align__(16) u8 As[2][16384];   // 128 rows * 128 B, x2
    __shared__ __align__(16) u8 Bs[2][8192];    //  64 rows * 128 B, x2

    const int bid = blockIdx.x;
    const int b = bid & 7;           // batch -> XCD spread
    const int t = bid >> 3;          // 0..71 upper-tile index

    int bi = 0;
#pragma unroll
    for (int i = 7; i >= 1; --i) {   // off(bi) = bi*(17-bi), increasing
        if (t >= i * (17 - i)) { bi = i; break; }
    }
    const int bj2 = 2 * bi + (t - bi * (17 - bi));   // 64-col block, 0..15
    const bool aliasB = (bj2 == 2 * bi) || (bj2 == 2 * bi + 1);

    const int tid  = threadIdx.x;
    const int lane = tid & 63;
    const int w    = tid >> 6;       // wave 0..3
    const int wm   = w >> 1;         // wave row-half (64 rows)
    const int wn   = w & 1;          // wave col-half (32 cols)

    // Staging: instr covers 8 rows x 8 slots. lane l -> row l>>3, slot l&7,
    // source kchunk = (l&7) ^ (l>>3).
    const int st_r  = lane >> 3;               // 0..7
    const int st_kc = (lane & 7) ^ st_r;       // source 16B-chunk

    const u8*    pA  = nullptr; const u8*    pB  = nullptr;
    const float* pAf = nullptr; const float* pBf = nullptr;
    if (QSRC) {
        const u8* baseX = Xq + (size_t)b * CCH * NHW;
        pA = baseX + (size_t)(bi * 128 + w * 32 + st_r) * NHW + st_kc * 16;
        pB = baseX + (size_t)(bj2 * 64 + w * 16 + st_r) * NHW + st_kc * 16;
    } else {
        const float* baseXf = Xf + (size_t)b * CCH * NHW;
        pAf = baseXf + (size_t)(bi * 128 + w * 32 + st_r) * NHW + st_kc * 16;
        pBf = baseXf + (size_t)(bj2 * 64 + w * 16 + st_r) * NHW + st_kc * 16;
    }

    float4v acc[4][2] = {};

    // ---- stage(buf, K0) ----
    auto stage = [&](int buf, int K0) {
        if (QSRC) {
#pragma unroll
            for (int t8 = 0; t8 < 4; ++t8)     // A: 32 rows per wave
                async_load16(pA + (size_t)(t8 * 8) * NHW + K0,
                             As[buf] + (size_t)(w * 32 + t8 * 8) * 128);
            if (!aliasB) {
#pragma unroll
                for (int t8 = 0; t8 < 2; ++t8) // B: 16 rows per wave
                    async_load16(pB + (size_t)(t8 * 8) * NHW + K0,
                                 Bs[buf] + (size_t)(w * 16 + t8 * 8) * 128);
            }
        } else {
#pragma unroll
            for (int t8 = 0; t8 < 4; ++t8) {
                const float* s = pAf + (size_t)(t8 * 8) * NHW + K0;
                float4 f0 = *(const float4*)(s);
                float4 f1 = *(const float4*)(s + 4);
                float4 f2 = *(const float4*)(s + 8);
                float4 f3 = *(const float4*)(s + 12);
                uint4v d;
                d.x = pk4_fp8(f0.x, f0.y, f0.z, f0.w);
                d.y = pk4_fp8(f1.x, f1.y, f1.z, f1.w);
                d.z = pk4_fp8(f2.x, f2.y, f2.z, f2.w);
                d.w = pk4_fp8(f3.x, f3.y, f3.z, f3.w);
                *(uint4v*)(As[buf] + (size_t)(w * 32 + t8 * 8 + st_r) * 128 + (lane & 7) * 16) = d;
            }
            if (!aliasB) {
#pragma unroll
                for (int t8 = 0; t8 < 2; ++t8) {
                    const float* s = pBf + (size_t)(t8 * 8) * NHW + K0;
                    float4 f0 = *(const float4*)(s);
                    float4 f1 = *(const float4*)(s + 4);
                    float4 f2 = *(const float4*)(s + 8);
                    float4 f3 = *(const float4*)(s + 12);
                    uint4v d;
                    d.x = pk4_fp8(f0.x, f0.y, f0.z, f0.w);
                    d.y = pk4_fp8(f1.x, f1.y, f1.z, f1.w);
                    d.z = pk4_fp8(f2.x, f2.y, f2.z, f2.w);
                    d.w = pk4_fp8(f3.x, f3.y, f3.z, f3.w);
                    *(uint4v*)(Bs[buf] + (size_t)(w * 16 + t8 * 8 + st_r) * 128 + (lane & 7) * 16) = d;
                }
            }
        }
    };

    stage(0, 0);
    __syncthreads();                 // publish buffer 0 (full drain, once)

    const int q   = lane >> 4;       // k-group 0..3: bytes [q*32, q*32+32)
    const int rl  = lane & 15;
    const int rl7 = rl & 7;
    const int c0  = 2 * q;           // base 16B chunk for this lane

    for (int i = 0; i < NHW / 128; ++i) {
        const int cur = i & 1;
        const int K0n = (i + 1) * 128;
        if (K0n < NHW) stage(cur ^ 1, K0n);   // prefetch BEFORE compute

        const u8* Ab = As[cur];
        const u8* Bb = aliasB ? (Ab + (size_t)(bj2 - 2 * bi) * 64 * 128) : Bs[cur];

        i32x8 af[4], bf[2];
#pragma unroll
        for (int mt = 0; mt < 4; ++mt) {
            const u8* p = Ab + (size_t)(wm * 64 + mt * 16 + rl) * 128;
            i32x4 lo = *(const i32x4*)(p + ((c0    ) ^ rl7) * 16);
            i32x4 hi = *(const i32x4*)(p + ((c0 + 1) ^ rl7) * 16);
            af[mt] = __builtin_shufflevector(lo, hi, 0, 1, 2, 3, 4, 5, 6, 7);
        }
#pragma unroll
        for (int nt = 0; nt < 2; ++nt) {
            const u8* p = Bb + (size_t)(wn * 32 + nt * 16 + rl) * 128;
            i32x4 lo = *(const i32x4*)(p + ((c0    ) ^ rl7) * 16);
            i32x4 hi = *(const i32x4*)(p + ((c0 + 1) ^ rl7) * 16);
            bf[nt] = __builtin_shufflevector(lo, hi, 0, 1, 2, 3, 4, 5, 6, 7);
        }
#pragma unroll
        for (int mt = 0; mt < 4; ++mt)
#pragma unroll
            for (int nt = 0; nt < 2; ++nt)
                acc[mt][nt] = __builtin_amdgcn_mfma_scale_f32_16x16x128_f8f6f4(
                    af[mt], bf[nt], acc[mt][nt],
                    0 /*cbsz: A=fp8 e4m3*/, 0 /*blgp: B=fp8 e4m3*/,
                    0, 127 /*scale A = 2^0*/, 0, 127 /*scale B = 2^0*/);
        __syncthreads();   // publish prefetched buffer (drain hidden behind compute)
    }

    // ---- Epilogue ----
    const int cl = lane & 15;    // col within 16
    const int rowbase = bi * 128 + wm * 64;
    const int colbase = bj2 * 64 + wn * 32;
    const float* dgb = diag + b * CCH;
    float* lb = l_acc + b * CCH;

    // Row sums (upper-inclusive) + diagonal numerator
#pragma unroll
    for (int mt = 0; mt < 4; ++mt) {
#pragma unroll
        for (int reg = 0; reg < 4; ++reg) {
            const int gr = rowbase + mt * 16 + q * 4 + reg;
            const float dg = dgb[gr];
            float s = 0.f;
#pragma unroll
            for (int nt = 0; nt < 2; ++nt) {
                const int gc = colbase + nt * 16 + cl;
                const float e = __expf(acc[mt][nt][reg] * SCALE - dg);
                if (gr <= gc) s += e;
                if (gr == gc) num[b * CCH + gr] = e;
            }
            s += __shfl_xor(s, 1);
            s += __shfl_xor(s, 2);
            s += __shfl_xor(s, 4);
            s += __shfl_xor(s, 8);
            if (cl == 0) atomicAdd(lb + gr, s);
        }
    }

    // Column sums (strictly-upper -> transposed contribution)
#pragma unroll
    for (int nt = 0; nt < 2; ++nt) {
        const int gc = colbase + nt * 16 + cl;
        const float dgc = dgb[gc];
        float s = 0.f;
#pragma unroll
        for (int mt = 0; mt < 4; ++mt) {
#pragma unroll
            for (int reg = 0; reg < 4; ++reg) {
                const int gr = rowbase + mt * 16 + q * 4 + reg;
                if (gr < gc) s += __expf(acc[mt][nt][reg] * SCALE - dgc);
            }
        }
        s += __shfl_xor(s, 16);
        s += __shfl_xor(s, 32);
        if (lane < 16) atomicAdd(lb + gc, s);
    }

    // ---- Fused finalize: last block to arrive reduces the loss ----
    __shared__ u32 lastflag;
    __threadfence();                 // release: this block's stores/atomics
    __syncthreads();
    if (tid == 0) {
        const u32 old = atomicAdd(counter, 1);
        lastflag = (old == (u32)(gridDim.x - 1)) ? 1u : 0u;
    }
    __syncthreads();
    if (lastflag) {
        __threadfence();             // acquire: see all blocks' num/l_acc
        float s = 0.f;
        for (int r = tid; r < ROWS; r += 256) {
            const float d = num[r] / l_acc[r];
            s += -__logf(d + 1e-10f);
        }
#pragma unroll
        for (int m = 1; m < 64; m <<= 1) s += __shfl_xor(s, m);
        __shared__ float red[4];
        if ((tid & 63) == 0) red[tid >> 6] = s;
        __syncthreads();
        if (tid == 0)
            out[0] = (red[0] + red[1] + red[2] + red[3]) * (1.0f / (float)ROWS);
    }
}

extern "C" void kernel_launch(void* const* d_in, const int* in_sizes, int n_in,
                              void* d_out, int out_size, void* d_ws, size_t ws_size,
                              hipStream_t stream) {
    const float* x = (const float*)d_in[0];
    float* out = (float*)d_out;

    const size_t xq_bytes   = (size_t)BATCH * CCH * NHW;      // 33554432 (fp8)
    const size_t stat_bytes = (size_t)ROWS * 4;               // 32768
    const bool fast = ws_size >= xq_bytes + 3 * stat_bytes + 64;

    const int ntiles = 72;  // 128x64 upper-triangle tiles per batch

    if (fast) {
        u8*    xq      = (u8*)d_ws;
        float* diag    = (float*)((char*)d_ws + xq_bytes);
        float* l_acc   = diag + ROWS;
        float* num     = l_acc + ROWS;
        u32*   counter = (u32*)(num + ROWS);
        prep_kernel<true><<<ROWS, 256, 0, stream>>>(x, xq, diag, l_acc, counter);
        gram_kernel<true><<<BATCH * ntiles, 256, 0, stream>>>(xq, nullptr, diag, l_acc, num, counter, out);
    } else {
        float* diag    = (float*)d_ws;
        float* l_acc   = diag + ROWS;
        float* num     = l_acc + ROWS;
        u32*   counter = (u32*)(num + ROWS);
        prep_kernel<false><<<ROWS, 256, 0, stream>>>(x, nullptr, diag, l_acc, counter);
        gram_kernel<false><<<BATCH * ntiles, 256, 0, stream>>>(nullptr, x, diag, l_acc, num, counter, out);
    }
}

// Round 2
// 264.545 us; speedup vs baseline: 1.1443x; 1.1443x over previous
//
#include <hip/hip_runtime.h>
#include <hip/hip_bf16.h>

#define BATCH 8
#define CCH 1024
#define NHW 4096
#define SCALE 5.0f   // 1/TEMPERATURE
#define ROWS (BATCH * CCH)

typedef unsigned char u8;
typedef unsigned int u32;
typedef __attribute__((ext_vector_type(4))) float float4v;
typedef __attribute__((ext_vector_type(4))) u32 uint4v;
typedef __attribute__((ext_vector_type(4))) int i32x4;
typedef __attribute__((ext_vector_type(8))) int i32x8;

// counted vmcnt wait — N must be a literal
#define VMW(N) asm volatile("s_waitcnt vmcnt(" #N ")" ::: "memory")

__device__ __forceinline__ void async_load16(const void* gsrc, void* ldst) {
    __builtin_amdgcn_global_load_lds(
        (__attribute__((address_space(1))) void*)gsrc,
        (__attribute__((address_space(3))) void*)ldst,
        16, 0, 0);
}

// pack 4 floats -> 4 OCP e4m3 bytes
__device__ __forceinline__ u32 pk4_fp8(float a, float b, float c, float d) {
    u32 v = __builtin_amdgcn_cvt_pk_fp8_f32(a, b, 0, false);
    v = __builtin_amdgcn_cvt_pk_fp8_f32(c, d, v, true);
    return v;
}

__device__ __forceinline__ float ssq4_fp8(u32 q) {
    float d0 = __builtin_amdgcn_cvt_f32_fp8(q, 0);
    float d1 = __builtin_amdgcn_cvt_f32_fp8(q, 1);
    float d2 = __builtin_amdgcn_cvt_f32_fp8(q, 2);
    float d3 = __builtin_amdgcn_cvt_f32_fp8(q, 3);
    return d0 * d0 + d1 * d1 + d2 * d2 + d3 * d3;
}

// One block per row: quantize x -> fp8, diag = 5*sum(q(x)^2) from QUANTIZED
// values (so the MFMA diagonal dot cancels), zero l_acc (+ completion counter).
template <bool CONVERT>
__global__ __launch_bounds__(256) void prep_kernel(const float* __restrict__ x,
                                                   u8* __restrict__ xq,
                                                   float* __restrict__ diag,
                                                   float* __restrict__ l_acc,
                                                   u32* __restrict__ counter) {
    const int row = blockIdx.x;          // 0..8191
    const int tid = threadIdx.x;
    const float* src = x + (size_t)row * NHW;
    float ssum = 0.f;
#pragma unroll
    for (int p = 0; p < 4; ++p) {
        const int idx = p * 1024 + tid * 4;
        float4 v = *(const float4*)(src + idx);
        const u32 q = pk4_fp8(v.x, v.y, v.z, v.w);
        ssum += ssq4_fp8(q);
        if (CONVERT) *(u32*)(xq + (size_t)row * NHW + idx) = q;
    }
#pragma unroll
    for (int m = 1; m < 64; m <<= 1) ssum += __shfl_xor(ssum, m);
    __shared__ float red[4];
    if ((tid & 63) == 0) red[tid >> 6] = ssum;
    __syncthreads();
    if (tid == 0) {
        diag[row] = (red[0] + red[1] + red[2] + red[3]) * SCALE;
        l_acc[row] = 0.f;
        if (row == 0) *counter = 0;
    }
}

// Symmetric Gram, fp8 e4m3, 128x64 tiles over upper triangle (bj2 >= 2*bi),
// BK=128, double-buffered. Inner loop: MX-scaled mfma_scale_f32_16x16x128
// with unit scales (e8m0=127) — one K=128 step of 8 MFMAs + 12 ds_read_b128.
//
// R1 fix (T3/T4): the per-iter __syncthreads() drained vmcnt(0), waiting for
// the SAME iteration's prefetch (latency fully exposed, MfmaUtil 6%). Now:
// counted s_waitcnt vmcnt(6|4) (only the CURRENT buffer's loads) + raw
// s_barrier pair — prefetch loads stay in flight across the barrier.
//
// LDS: row = 128 B = 8 chunks of 16 B; chunk (r, kc) at slot kc ^ (r&7).
// Tiles with bj2 in {2bi, 2bi+1}: B rows subset of A rows -> alias As.
// Last block to finish (device counter) performs the scalar finalize.
template <bool QSRC>
__global__ __launch_bounds__(256) void gram_kernel(const u8* __restrict__ Xq,
                                                   const float* __restrict__ Xf,
                                                   const float* __restrict__ diag,
                                                   float* __restrict__ l_acc,
                                                   float* __restrict__ num,
                                                   u32* __restrict__ counter,
                                                   float* __restrict__ out) {
    __shared__ __align__(16) u8 As[2][16384];   // 128 rows * 128 B, x2
    __shared__ __align__(16) u8 Bs[2][8192];    //  64 rows * 128 B, x2

    const int bid = blockIdx.x;
    const int b = bid & 7;           // batch -> XCD spread
    const int t = bid >> 3;          // 0..71 upper-tile index

    int bi = 0;
#pragma unroll
    for (int i = 7; i >= 1; --i) {   // off(bi) = bi*(17-bi), increasing
        if (t >= i * (17 - i)) { bi = i; break; }
    }
    const int bj2 = 2 * bi + (t - bi * (17 - bi));   // 64-col block, 0..15
    const bool aliasB = (bj2 == 2 * bi) || (bj2 == 2 * bi + 1);

    const int tid  = threadIdx.x;
    const int lane = tid & 63;
    const int w    = tid >> 6;       // wave 0..3
    const int wm   = w >> 1;         // wave row-half (64 rows)
    const int wn   = w & 1;          // wave col-half (32 cols)

    // Staging: instr covers 8 rows x 8 slots. lane l -> row l>>3, slot l&7,
    // source kchunk = (l&7) ^ (l>>3).
    const int st_r  = lane >> 3;               // 0..7
    const int st_kc = (lane & 7) ^ st_r;       // source 16B-chunk

    const u8*    pA  = nullptr; const u8*    pB  = nullptr;
    const float* pAf = nullptr; const float* pBf = nullptr;
    if (QSRC) {
        const u8* baseX = Xq + (size_t)b * CCH * NHW;
        pA = baseX + (size_t)(bi * 128 + w * 32 + st_r) * NHW + st_kc * 16;
        pB = baseX + (size_t)(bj2 * 64 + w * 16 + st_r) * NHW + st_kc * 16;
    } else {
        const float* baseXf = Xf + (size_t)b * CCH * NHW;
        pAf = baseXf + (size_t)(bi * 128 + w * 32 + st_r) * NHW + st_kc * 16;
        pBf = baseXf + (size_t)(bj2 * 64 + w * 16 + st_r) * NHW + st_kc * 16;
    }

    float4v acc[4][2] = {};

    // ---- stage(buf, K0) ----
    auto stage = [&](int buf, int K0) {
        if (QSRC) {
#pragma unroll
            for (int t8 = 0; t8 < 4; ++t8)     // A: 32 rows per wave
                async_load16(pA + (size_t)(t8 * 8) * NHW + K0,
                             As[buf] + (size_t)(w * 32 + t8 * 8) * 128);
            if (!aliasB) {
#pragma unroll
                for (int t8 = 0; t8 < 2; ++t8) // B: 16 rows per wave
                    async_load16(pB + (size_t)(t8 * 8) * NHW + K0,
                                 Bs[buf] + (size_t)(w * 16 + t8 * 8) * 128);
            }
        } else {
#pragma unroll
            for (int t8 = 0; t8 < 4; ++t8) {
                const float* s = pAf + (size_t)(t8 * 8) * NHW + K0;
                float4 f0 = *(const float4*)(s);
                float4 f1 = *(const float4*)(s + 4);
                float4 f2 = *(const float4*)(s + 8);
                float4 f3 = *(const float4*)(s + 12);
                uint4v d;
                d.x = pk4_fp8(f0.x, f0.y, f0.z, f0.w);
                d.y = pk4_fp8(f1.x, f1.y, f1.z, f1.w);
                d.z = pk4_fp8(f2.x, f2.y, f2.z, f2.w);
                d.w = pk4_fp8(f3.x, f3.y, f3.z, f3.w);
                *(uint4v*)(As[buf] + (size_t)(w * 32 + t8 * 8 + st_r) * 128 + (lane & 7) * 16) = d;
            }
            if (!aliasB) {
#pragma unroll
                for (int t8 = 0; t8 < 2; ++t8) {
                    const float* s = pBf + (size_t)(t8 * 8) * NHW + K0;
                    float4 f0 = *(const float4*)(s);
                    float4 f1 = *(const float4*)(s + 4);
                    float4 f2 = *(const float4*)(s + 8);
                    float4 f3 = *(const float4*)(s + 12);
                    uint4v d;
                    d.x = pk4_fp8(f0.x, f0.y, f0.z, f0.w);
                    d.y = pk4_fp8(f1.x, f1.y, f1.z, f1.w);
                    d.z = pk4_fp8(f2.x, f2.y, f2.z, f2.w);
                    d.w = pk4_fp8(f3.x, f3.y, f3.z, f3.w);
                    *(uint4v*)(Bs[buf] + (size_t)(w * 16 + t8 * 8 + st_r) * 128 + (lane & 7) * 16) = d;
                }
            }
        }
    };

    stage(0, 0);
    if (!QSRC) __syncthreads();      // fallback: publish buffer 0 (full drain)

    const int q   = lane >> 4;       // k-group 0..3: bytes [q*32, q*32+32)
    const int rl  = lane & 15;
    const int rl7 = rl & 7;
    const int c0  = 2 * q;           // base 16B chunk for this lane

    for (int i = 0; i < NHW / 128; ++i) {
        const int cur = i & 1;
        const int K0n = (i + 1) * 128;
        const bool more = (K0n < NHW);
        if (more) stage(cur ^ 1, K0n);   // prefetch BEFORE compute

        if (QSRC) {
            // Wait only for the CURRENT buffer's DMAs (issued last iter);
            // the 'more' prefetch (6 or 4 loads) stays in flight.
            if (more) {
                if (aliasB) VMW(4); else VMW(6);
            } else {
                VMW(0);
            }
            __builtin_amdgcn_s_barrier();        // all waves: cur published
            __builtin_amdgcn_sched_barrier(0);   // no ds_read hoisting
        } else {
            __syncthreads();
        }

        const u8* Ab = As[cur];
        const u8* Bb = aliasB ? (Ab + (size_t)(bj2 - 2 * bi) * 64 * 128) : Bs[cur];

        i32x8 af[4], bf[2];
#pragma unroll
        for (int mt = 0; mt < 4; ++mt) {
            const u8* p = Ab + (size_t)(wm * 64 + mt * 16 + rl) * 128;
            i32x4 lo = *(const i32x4*)(p + ((c0    ) ^ rl7) * 16);
            i32x4 hi = *(const i32x4*)(p + ((c0 + 1) ^ rl7) * 16);
            af[mt] = __builtin_shufflevector(lo, hi, 0, 1, 2, 3, 4, 5, 6, 7);
        }
#pragma unroll
        for (int nt = 0; nt < 2; ++nt) {
            const u8* p = Bb + (size_t)(wn * 32 + nt * 16 + rl) * 128;
            i32x4 lo = *(const i32x4*)(p + ((c0    ) ^ rl7) * 16);
            i32x4 hi = *(const i32x4*)(p + ((c0 + 1) ^ rl7) * 16);
            bf[nt] = __builtin_shufflevector(lo, hi, 0, 1, 2, 3, 4, 5, 6, 7);
        }
#pragma unroll
        for (int mt = 0; mt < 4; ++mt)
#pragma unroll
            for (int nt = 0; nt < 2; ++nt)
                acc[mt][nt] = __builtin_amdgcn_mfma_scale_f32_16x16x128_f8f6f4(
                    af[mt], bf[nt], acc[mt][nt],
                    0 /*cbsz: A=fp8 e4m3*/, 0 /*blgp: B=fp8 e4m3*/,
                    0, 127 /*scale A = 2^0*/, 0, 127 /*scale B = 2^0*/);

        if (QSRC) {
            __builtin_amdgcn_sched_barrier(0);   // keep ds_reads before barrier
            __builtin_amdgcn_s_barrier();        // cur fully read -> safe to overwrite
        } else {
            __syncthreads();
        }
    }

    // ---- Epilogue ----
    const int cl = lane & 15;    // col within 16
    const int rowbase = bi * 128 + wm * 64;
    const int colbase = bj2 * 64 + wn * 32;
    const float* dgb = diag + b * CCH;
    float* lb = l_acc + b * CCH;

    // Row sums (upper-inclusive) + diagonal numerator
#pragma unroll
    for (int mt = 0; mt < 4; ++mt) {
#pragma unroll
        for (int reg = 0; reg < 4; ++reg) {
            const int gr = rowbase + mt * 16 + q * 4 + reg;
            const float dg = dgb[gr];
            float s = 0.f;
#pragma unroll
            for (int nt = 0; nt < 2; ++nt) {
                const int gc = colbase + nt * 16 + cl;
                const float e = __expf(acc[mt][nt][reg] * SCALE - dg);
                if (gr <= gc) s += e;
                if (gr == gc) num[b * CCH + gr] = e;
            }
            s += __shfl_xor(s, 1);
            s += __shfl_xor(s, 2);
            s += __shfl_xor(s, 4);
            s += __shfl_xor(s, 8);
            if (cl == 0) atomicAdd(lb + gr, s);
        }
    }

    // Column sums (strictly-upper -> transposed contribution)
#pragma unroll
    for (int nt = 0; nt < 2; ++nt) {
        const int gc = colbase + nt * 16 + cl;
        const float dgc = dgb[gc];
        float s = 0.f;
#pragma unroll
        for (int mt = 0; mt < 4; ++mt) {
#pragma unroll
            for (int reg = 0; reg < 4; ++reg) {
                const int gr = rowbase + mt * 16 + q * 4 + reg;
                if (gr < gc) s += __expf(acc[mt][nt][reg] * SCALE - dgc);
            }
        }
        s += __shfl_xor(s, 16);
        s += __shfl_xor(s, 32);
        if (lane < 16) atomicAdd(lb + gc, s);
    }

    // ---- Fused finalize: last block to arrive reduces the loss ----
    __shared__ u32 lastflag;
    __threadfence();                 // release: this block's stores/atomics
    __syncthreads();
    if (tid == 0) {
        const u32 old = atomicAdd(counter, 1);
        lastflag = (old == (u32)(gridDim.x - 1)) ? 1u : 0u;
    }
    __syncthreads();
    if (lastflag) {
        __threadfence();             // acquire: see all blocks' num/l_acc
        float s = 0.f;
        for (int r = tid; r < ROWS; r += 256) {
            const float d = num[r] / l_acc[r];
            s += -__logf(d + 1e-10f);
        }
#pragma unroll
        for (int m = 1; m < 64; m <<= 1) s += __shfl_xor(s, m);
        __shared__ float red[4];
        if ((tid & 63) == 0) red[tid >> 6] = s;
        __syncthreads();
        if (tid == 0)
            out[0] = (red[0] + red[1] + red[2] + red[3]) * (1.0f / (float)ROWS);
    }
}

extern "C" void kernel_launch(void* const* d_in, const int* in_sizes, int n_in,
                              void* d_out, int out_size, void* d_ws, size_t ws_size,
                              hipStream_t stream) {
    const float* x = (const float*)d_in[0];
    float* out = (float*)d_out;

    const size_t xq_bytes   = (size_t)BATCH * CCH * NHW;      // 33554432 (fp8)
    const size_t stat_bytes = (size_t)ROWS * 4;               // 32768
    const bool fast = ws_size >= xq_bytes + 3 * stat_bytes + 64;

    const int ntiles = 72;  // 128x64 upper-triangle tiles per batch

    if (fast) {
        u8*    xq      = (u8*)d_ws;
        float* diag    = (float*)((char*)d_ws + xq_bytes);
        float* l_acc   = diag + ROWS;
        float* num     = l_acc + ROWS;
        u32*   counter = (u32*)(num + ROWS);
        prep_kernel<true><<<ROWS, 256, 0, stream>>>(x, xq, diag, l_acc, counter);
        gram_kernel<true><<<BATCH * ntiles, 256, 0, stream>>>(xq, nullptr, diag, l_acc, num, counter, out);
    } else {
        float* diag    = (float*)d_ws;
        float* l_acc   = diag + ROWS;
        float* num     = l_acc + ROWS;
        u32*   counter = (u32*)(num + ROWS);
        prep_kernel<false><<<ROWS, 256, 0, stream>>>(x, nullptr, diag, l_acc, counter);
        gram_kernel<false><<<BATCH * ntiles, 256, 0, stream>>>(nullptr, x, diag, l_acc, num, counter, out);
    }
}